// Round 3
// baseline (222.088 us; speedup 1.0000x reference)
//
#include <hip/hip_runtime.h>
#include <hip/hip_bf16.h>
#include <math.h>

typedef unsigned int uint;

// ---- ws layout (uint word offsets) ----
#define WB4   0      // uint4[4*32]: per (k,o): {wa,wb,wc,(uint)T}  words 0..511
#define L1S   512    // uint4[32]: layer1 sign masks (0 / 0x80000000 per input ch)
#define L1T   640    // float[32]: layer1 thresholds
#define W1T   672    // uint[16*64]: fc1 packed, [i][j] (i=position, j=out)
#define T5O   1696   // int[64]
#define W2T   1760   // uint[2*64]: fc2 packed, [h][j]
#define T6O   1888   // int[64]
#define W3O   1952   // uint[2]
#define FB3O  1954   // float fc3_b
#define TOTW  1955

// LDS mirror covers [W1T, TOTW)
#define ST5   (T5O - W1T)   // 1024
#define SW2   (W2T - W1T)   // 1088
#define ST6   (T6O - W1T)   // 1216
#define SW3   (W3O - W1T)   // 1280
#define SFB3  (FB3O - W1T)  // 1282
#define SMTOT (TOTW - W1T)  // 1283

// exact replication of the reference BN chain: r = ((v+cb)-m)*sc + b
__device__ __forceinline__ float bnr(float v, float cb, float m, float sc, float b) {
  return __fadd_rn(__fmul_rn(__fsub_rn(__fadd_rn(v, cb), m), sc), b);
}

// first integer c in [lo,hi] whose (possibly negated) BN result is >= 0
__device__ __forceinline__ int iscan(int lo, int hi, int dir,
                                     float cb, float m, float sc, float b) {
  for (int c = lo; c <= hi; ++c) {
    float vf = (float)(dir ? -c : c);
    if (bnr(vf, cb, m, sc, b) >= 0.f) return c;
  }
  return hi + 1;  // never true
}

// sortable-key <-> float
__device__ __forceinline__ float key2f(uint k) {
  return __uint_as_float((k & 0x80000000u) ? (k ^ 0x80000000u) : ~k);
}

// minimal float d' (ordered) with bnr(dir ? -d' : d') >= 0  (monotone chain)
__device__ __forceinline__ float fsearch(int dir, float cb, float m, float sc, float b) {
  uint lo = 0x00800000u;   // key(-FLT_MAX)
  uint hi = 0xFF7FFFFFu;   // key(+FLT_MAX)
  float fhi = key2f(hi);
  if (!(bnr(dir ? -fhi : fhi, cb, m, sc, b) >= 0.f))
    return __uint_as_float(0x7F800000u);  // +inf : never true
  while (lo < hi) {
    uint mid = lo + ((hi - lo) >> 1);
    float fm = key2f(mid);
    if (bnr(dir ? -fm : fm, cb, m, sc, b) >= 0.f) hi = mid; else lo = mid + 1;
  }
  return key2f(lo);
}

__global__ void prep_kernel(
    const float* __restrict__ conv0_w, const float* __restrict__ conv0_b,
    const float* __restrict__ bn0_g, const float* __restrict__ bn0_b,
    const float* __restrict__ bn0_m, const float* __restrict__ bn0_v,
    const float* __restrict__ convs_w, const float* __restrict__ convs_b,
    const float* __restrict__ bns_g, const float* __restrict__ bns_b,
    const float* __restrict__ bns_m, const float* __restrict__ bns_v,
    const float* __restrict__ fc1_w, const float* __restrict__ fc1_b,
    const float* __restrict__ bn5_g, const float* __restrict__ bn5_b,
    const float* __restrict__ bn5_m, const float* __restrict__ bn5_v,
    const float* __restrict__ fc2_w, const float* __restrict__ fc2_b,
    const float* __restrict__ bn6_g, const float* __restrict__ bn6_b,
    const float* __restrict__ bn6_m, const float* __restrict__ bn6_v,
    const float* __restrict__ fc3_w, const float* __restrict__ fc3_b,
    uint* __restrict__ ws)
{
  const int t0 = blockIdx.x * blockDim.x + threadIdx.x;
  const int NT = gridDim.x * blockDim.x;
  for (int task = t0; task < 1443; task += NT) {
    if (task < 32) {
      // layer1 channel o: sign masks + float threshold
      int o = task;
      float sc = bn0_g[o] / sqrtf(bn0_v[o] + 0.01f);
      int dir = sc < 0.f;
      uint fm = dir ? 0x80000000u : 0u;
      uint4 sg;
      sg.x = ((conv0_w[o*4+0] >= 0.f) ? 0u : 0x80000000u) ^ fm;
      sg.y = ((conv0_w[o*4+1] >= 0.f) ? 0u : 0x80000000u) ^ fm;
      sg.z = ((conv0_w[o*4+2] >= 0.f) ? 0u : 0x80000000u) ^ fm;
      sg.w = ((conv0_w[o*4+3] >= 0.f) ? 0u : 0x80000000u) ^ fm;
      ((uint4*)(ws + L1S))[o] = sg;
      ((float*)(ws + L1T))[o] = fsearch(dir, conv0_b[o], bn0_m[o], sc, bn0_b[o]);
    } else if (task < 160) {
      // conv block (k,o): packed taps + int threshold
      int idx = task - 32, k = idx >> 5, o = idx & 31, ko = k * 32 + o;
      float sc = bns_g[ko] / sqrtf(bns_v[ko] + 0.01f);
      int dir = sc < 0.f;
      uint fm = dir ? 0xFFFFFFFFu : 0u;
      uint wv[3];
      for (int d = 0; d < 3; ++d) {
        uint w = 0;
        for (int c = 0; c < 32; ++c)
          if (convs_w[(ko * 32 + c) * 3 + d] >= 0.f) w |= 1u << c;
        wv[d] = w ^ fm;
      }
      int T = iscan(-384, 384, dir, convs_b[ko], bns_m[ko], sc, bns_b[ko]);
      uint4 pk; pk.x = wv[0]; pk.y = wv[1]; pk.z = wv[2]; pk.w = (uint)T;
      ((uint4*)(ws + WB4))[ko] = pk;
    } else if (task < 1184) {
      // fc1 packed word [i][j]
      int u = task - 160, i = u >> 6, j = u & 63;
      float sc = bn5_g[j] / sqrtf(bn5_v[j] + 0.01f);
      uint fm = (sc < 0.f) ? 0xFFFFFFFFu : 0u;
      uint w = 0;
      for (int c = 0; c < 32; ++c)
        if (fc1_w[j * 512 + c * 16 + i] >= 0.f) w |= 1u << c;
      ws[W1T + i * 64 + j] = w ^ fm;
    } else if (task < 1248) {
      int j = task - 1184;
      float sc = bn5_g[j] / sqrtf(bn5_v[j] + 0.01f);
      int dir = sc < 0.f;
      ((int*)ws)[T5O + j] = iscan(-1024, 1024, dir, fc1_b[j], bn5_m[j], sc, bn5_b[j]);
    } else if (task < 1376) {
      // fc2 packed word [h][j]
      int u = task - 1248, h = u >> 6, j = u & 63;
      float sc = bn6_g[j] / sqrtf(bn6_v[j] + 0.01f);
      uint fm = (sc < 0.f) ? 0xFFFFFFFFu : 0u;
      uint w = 0;
      for (int c = 0; c < 32; ++c)
        if (fc2_w[j * 64 + h * 32 + c] >= 0.f) w |= 1u << c;
      ws[W2T + h * 64 + j] = w ^ fm;
    } else if (task < 1440) {
      int j = task - 1376;
      float sc = bn6_g[j] / sqrtf(bn6_v[j] + 0.01f);
      int dir = sc < 0.f;
      ((int*)ws)[T6O + j] = iscan(-64, 64, dir, fc2_b[j], bn6_m[j], sc, bn6_b[j]);
    } else if (task < 1442) {
      int h = task - 1440;
      uint w = 0;
      for (int c = 0; c < 32; ++c)
        if (fc3_w[h * 32 + c] >= 0.f) w |= 1u << c;
      ws[W3O + h] = w;
    } else {
      ((float*)ws)[FB3O] = fc3_b[0];
    }
  }
}

// 8 lanes per sample; lane l owns positions 2l, 2l+1.
__global__ __launch_bounds__(256, 6) void bnn_kernel(const float* __restrict__ x,
                                                     const uint* __restrict__ ws,
                                                     float* __restrict__ out,
                                                     int B)
{
  __shared__ uint sm[SMTOT];
  for (int i = threadIdx.x; i < SMTOT; i += 256) sm[i] = ws[W1T + i];
  __syncthreads();
  const int gt = blockIdx.x * 256 + threadIdx.x;
  const int b = gt >> 3;
  const int l = gt & 7;
  if (b >= B) return;
  const bool hasL = (l > 0), hasR = (l < 7);
  const uint mL = hasL ? ~0u : 0u;
  const uint mR = hasR ? ~0u : 0u;

  // ---- load x[b]: 4 channels x 2 owned positions (as raw bits) ----
  uint xu0[4], xu1[4];
  const float2* xp = (const float2*)(x + (size_t)b * 64 + 2 * l);
#pragma unroll
  for (int c = 0; c < 4; ++c) {
    float2 v = xp[c * 8];
    xu0[c] = __float_as_uint(v.x);
    xu1[c] = __float_as_uint(v.y);
  }

  // ---- layer 1: sign-xor products + threshold compare ----
  const uint4* l1s = (const uint4*)(ws + L1S);
  const float* l1t = (const float*)(ws + L1T);
  uint s0v0 = 0, s0v1 = 0;
  for (int o = 0; o < 32; ++o) {
    uint4 sg = l1s[o];
    float tf = l1t[o];
    float d0 = __fadd_rn(__fadd_rn(__fadd_rn(
                  __uint_as_float(xu0[0] ^ sg.x),
                  __uint_as_float(xu0[1] ^ sg.y)),
                  __uint_as_float(xu0[2] ^ sg.z)),
                  __uint_as_float(xu0[3] ^ sg.w));
    float d1 = __fadd_rn(__fadd_rn(__fadd_rn(
                  __uint_as_float(xu1[0] ^ sg.x),
                  __uint_as_float(xu1[1] ^ sg.y)),
                  __uint_as_float(xu1[2] ^ sg.z)),
                  __uint_as_float(xu1[3] ^ sg.w));
    if (d0 >= tf) s0v0 |= 1u << o;
    if (d1 >= tf) s0v1 |= 1u << o;
  }

  const uint s0l = (uint)__shfl_up((int)s0v1, 1);
  const uint s0r = (uint)__shfl_down((int)s0v0, 1);

  uint cur0, cur1;

  // ---- block 0: binary conv, integer threshold ----
  {
    const int M0 = hasL ? 96 : 64;
    const int M1 = hasR ? 96 : 64;
    const uint4* wb4 = (const uint4*)(ws + WB4);
    uint n0 = 0, n1 = 0;
    for (int o = 0; o < 32; ++o) {
      uint4 w = wb4[o];
      int T = (int)w.w;
      int pc0 = __popc(s0v0 ^ w.y) + __popc((s0l ^ w.x) & mL) + __popc(s0v1 ^ w.z);
      int pc1 = __popc(s0v1 ^ w.y) + __popc(s0v0 ^ w.x) + __popc((s0r ^ w.z) & mR);
      if (M0 - 2 * pc0 >= T) n0 |= 1u << o;
      if (M1 - 2 * pc1 >= T) n1 |= 1u << o;
    }
    cur0 = n0; cur1 = n1;
  }

  // ---- blocks 1..3: ternary (sign(prev)+s0) via agree masks, int thresholds ----
  for (int k = 1; k < 4; ++k) {
    const uint cl = (uint)__shfl_up((int)cur1, 1);
    const uint cr = (uint)__shfl_down((int)cur0, 1);
    const uint e0 = ~(cur0 ^ s0v0);
    const uint e1 = ~(cur1 ^ s0v1);
    const uint el = (~(cl ^ s0l)) & mL;
    const uint er = (~(cr ^ s0r)) & mR;
    const int pe0 = __popc(e0), pe1 = __popc(e1);
    const int P2_0 = 2 * (__popc(el) + pe0 + pe1);
    const int P2_1 = 2 * (pe0 + pe1 + __popc(er));
    const uint4* wb4 = (const uint4*)(ws + WB4) + k * 32;
    uint n0 = 0, n1 = 0;
    for (int o = 0; o < 32; ++o) {
      uint4 w = wb4[o];
      int T = (int)w.w;
      int pc0 = __popc((cur0 ^ w.y) & e0) + __popc((cl ^ w.x) & el)
              + __popc((cur1 ^ w.z) & e1);
      int pc1 = __popc((cur1 ^ w.y) & e1) + __popc((cur0 ^ w.x) & e0)
              + __popc((cr ^ w.z) & er);
      if (P2_0 - 4 * pc0 >= T) n0 |= 1u << o;
      if (P2_1 - 4 * pc1 >= T) n1 |= 1u << o;
    }
    cur0 = n0; cur1 = n1;
  }

  // ---- all-gather 16 position words + agree masks across the 8-lane group ----
  const int gbase = (threadIdx.x & 63) & ~7;
  uint curF[16], eF[16];
  int E = 0;
#pragma unroll
  for (int i = 0; i < 16; ++i) {
    int src = gbase + (i >> 1);
    uint cw = (uint)__shfl((i & 1) ? (int)cur1 : (int)cur0, src);
    uint sw = (uint)__shfl((i & 1) ? (int)s0v1 : (int)s0v0, src);
    curF[i] = cw;
    eF[i] = ~(cw ^ sw);
    E += __popc(eF[i]);
  }
  const int E2 = 2 * E;

  // ---- fc1: 8 outputs per lane, int thresholds ----
  uint hbits = 0;
  for (int jj = 0; jj < 8; ++jj) {
    int j = l * 8 + jj;
    int pc = 0;
#pragma unroll
    for (int i = 0; i < 16; ++i)
      pc += __popc((curF[i] ^ sm[i * 64 + j]) & eF[i]);
    if (E2 - 4 * pc >= (int)sm[ST5 + j]) hbits |= 1u << jj;
  }
  uint hh = hbits << ((l & 3) * 8);
  uint h0 = (l < 4) ? hh : 0u;
  uint h1 = (l < 4) ? 0u : hh;
  h0 |= (uint)__shfl_xor((int)h0, 1); h0 |= (uint)__shfl_xor((int)h0, 2); h0 |= (uint)__shfl_xor((int)h0, 4);
  h1 |= (uint)__shfl_xor((int)h1, 1); h1 |= (uint)__shfl_xor((int)h1, 2); h1 |= (uint)__shfl_xor((int)h1, 4);

  // ---- fc2: 8 outputs per lane ----
  uint gbits = 0;
  for (int jj = 0; jj < 8; ++jj) {
    int j = l * 8 + jj;
    int pc = __popc(h0 ^ sm[SW2 + j]) + __popc(h1 ^ sm[SW2 + 64 + j]);
    if (64 - 2 * pc >= (int)sm[ST6 + j]) gbits |= 1u << jj;
  }
  uint gg = gbits << ((l & 3) * 8);
  uint g0 = (l < 4) ? gg : 0u;
  uint g1 = (l < 4) ? 0u : gg;
  g0 |= (uint)__shfl_xor((int)g0, 1); g0 |= (uint)__shfl_xor((int)g0, 2); g0 |= (uint)__shfl_xor((int)g0, 4);
  g1 |= (uint)__shfl_xor((int)g1, 1); g1 |= (uint)__shfl_xor((int)g1, 2); g1 |= (uint)__shfl_xor((int)g1, 4);

  // ---- fc3 + sigmoid ----
  if (l == 0) {
    int pc = __popc(g0 ^ sm[SW3]) + __popc(g1 ^ sm[SW3 + 1]);
    float z = __fadd_rn((float)(64 - 2 * pc), __uint_as_float(sm[SFB3]));
    out[b] = 1.f / (1.f + expf(-z));
  }
}

extern "C" void kernel_launch(void* const* d_in, const int* in_sizes, int n_in,
                              void* d_out, int out_size, void* d_ws, size_t ws_size,
                              hipStream_t stream) {
  const float* x       = (const float*)d_in[0];
  const float* conv0_w = (const float*)d_in[1];
  const float* conv0_b = (const float*)d_in[2];
  const float* bn0_g   = (const float*)d_in[3];
  const float* bn0_b   = (const float*)d_in[4];
  const float* bn0_m   = (const float*)d_in[5];
  const float* bn0_v   = (const float*)d_in[6];
  const float* convs_w = (const float*)d_in[7];
  const float* convs_b = (const float*)d_in[8];
  const float* bns_g   = (const float*)d_in[9];
  const float* bns_b   = (const float*)d_in[10];
  const float* bns_m   = (const float*)d_in[11];
  const float* bns_v   = (const float*)d_in[12];
  const float* fc1_w   = (const float*)d_in[13];
  const float* fc1_b   = (const float*)d_in[14];
  const float* bn5_g   = (const float*)d_in[15];
  const float* bn5_b   = (const float*)d_in[16];
  const float* bn5_m   = (const float*)d_in[17];
  const float* bn5_v   = (const float*)d_in[18];
  const float* fc2_w   = (const float*)d_in[19];
  const float* fc2_b   = (const float*)d_in[20];
  const float* bn6_g   = (const float*)d_in[21];
  const float* bn6_b   = (const float*)d_in[22];
  const float* bn6_m   = (const float*)d_in[23];
  const float* bn6_v   = (const float*)d_in[24];
  const float* fc3_w   = (const float*)d_in[25];
  const float* fc3_b   = (const float*)d_in[26];
  uint* ws = (uint*)d_ws;

  hipLaunchKernelGGL(prep_kernel, dim3(6), dim3(256), 0, stream,
                     conv0_w, conv0_b, bn0_g, bn0_b, bn0_m, bn0_v,
                     convs_w, convs_b, bns_g, bns_b, bns_m, bns_v,
                     fc1_w, fc1_b, bn5_g, bn5_b, bn5_m, bn5_v,
                     fc2_w, fc2_b, bn6_g, bn6_b, bn6_m, bn6_v,
                     fc3_w, fc3_b, ws);

  const int B = in_sizes[0] / 64;   // 65536
  const int threads = B * 8;        // 8 lanes per sample
  hipLaunchKernelGGL(bnn_kernel, dim3((threads + 255) / 256), dim3(256), 0, stream,
                     x, ws, (float*)d_out, B);
}

// Round 4
// 181.976 us; speedup vs baseline: 1.2204x; 1.2204x over previous
//
#include <hip/hip_runtime.h>
#include <hip/hip_bf16.h>
#include <math.h>

typedef unsigned int uint;

// ---- ws layout (uint word offsets) ----
#define WB4   0      // uint4[4*32]: per (k,o): {wa,wb,wc,(uint)T}  words 0..511
#define L1S   512    // uint4[32]: layer1 sign masks (0 / 0x80000000 per input ch)
#define L1T   640    // float[32]: layer1 thresholds
#define W1T   672    // uint[16*64]: fc1 packed, TRANSPOSED+SWIZZLED [j][i] image for LDS
#define T5O   1696   // int[64]
#define W2T   1760   // uint[2*64]: fc2 packed, [h][j]
#define T6O   1888   // int[64]
#define W3O   1952   // uint[2]
#define FB3O  1954   // float fc3_b
#define TOTW  1955

// LDS mirror covers [W1T, TOTW)
#define ST5   (T5O - W1T)   // 1024
#define SW2   (W2T - W1T)   // 1088
#define ST6   (T6O - W1T)   // 1216
#define SW3   (W3O - W1T)   // 1280
#define SFB3  (FB3O - W1T)  // 1282
#define SMTOT (TOTW - W1T)  // 1283

// exact replication of the reference BN chain: r = ((v+cb)-m)*sc + b
__device__ __forceinline__ float bnr(float v, float cb, float m, float sc, float b) {
  return __fadd_rn(__fmul_rn(__fsub_rn(__fadd_rn(v, cb), m), sc), b);
}

// min integer c in [lo,hi] with bnr(dir ? -c : c) >= 0 (monotone), else hi+1
__device__ __forceinline__ int ibs(int lo, int hi, int dir,
                                   float cb, float m, float sc, float b) {
  int ans = hi + 1;
  while (lo <= hi) {
    int mid = lo + ((hi - lo) >> 1);
    float vf = (float)(dir ? -mid : mid);
    if (bnr(vf, cb, m, sc, b) >= 0.f) { ans = mid; hi = mid - 1; }
    else lo = mid + 1;
  }
  return ans;
}

// sortable-key <-> float
__device__ __forceinline__ float key2f(uint k) {
  return __uint_as_float((k & 0x80000000u) ? (k ^ 0x80000000u) : ~k);
}

// minimal float d' (ordered) with bnr(dir ? -d' : d') >= 0  (monotone chain)
__device__ __forceinline__ float fsearch(int dir, float cb, float m, float sc, float b) {
  uint lo = 0x00800000u;   // key(-FLT_MAX)
  uint hi = 0xFF7FFFFFu;   // key(+FLT_MAX)
  float fhi = key2f(hi);
  if (!(bnr(dir ? -fhi : fhi, cb, m, sc, b) >= 0.f))
    return __uint_as_float(0x7F800000u);  // +inf : never true
  while (lo < hi) {
    uint mid = lo + ((hi - lo) >> 1);
    float fm = key2f(mid);
    if (bnr(dir ? -fm : fm, cb, m, sc, b) >= 0.f) hi = mid; else lo = mid + 1;
  }
  return key2f(lo);
}

__global__ void prep_kernel(
    const float* __restrict__ conv0_w, const float* __restrict__ conv0_b,
    const float* __restrict__ bn0_g, const float* __restrict__ bn0_b,
    const float* __restrict__ bn0_m, const float* __restrict__ bn0_v,
    const float* __restrict__ convs_w, const float* __restrict__ convs_b,
    const float* __restrict__ bns_g, const float* __restrict__ bns_b,
    const float* __restrict__ bns_m, const float* __restrict__ bns_v,
    const float* __restrict__ fc1_w, const float* __restrict__ fc1_b,
    const float* __restrict__ bn5_g, const float* __restrict__ bn5_b,
    const float* __restrict__ bn5_m, const float* __restrict__ bn5_v,
    const float* __restrict__ fc2_w, const float* __restrict__ fc2_b,
    const float* __restrict__ bn6_g, const float* __restrict__ bn6_b,
    const float* __restrict__ bn6_m, const float* __restrict__ bn6_v,
    const float* __restrict__ fc3_w, const float* __restrict__ fc3_b,
    uint* __restrict__ ws)
{
  const int t0 = blockIdx.x * blockDim.x + threadIdx.x;
  const int NT = gridDim.x * blockDim.x;
  for (int task = t0; task < 1443; task += NT) {
    if (task < 32) {
      // layer1 channel o: sign masks + float threshold
      int o = task;
      float sc = bn0_g[o] / sqrtf(bn0_v[o] + 0.01f);
      int dir = sc < 0.f;
      uint fm = dir ? 0x80000000u : 0u;
      uint4 sg;
      sg.x = ((conv0_w[o*4+0] >= 0.f) ? 0u : 0x80000000u) ^ fm;
      sg.y = ((conv0_w[o*4+1] >= 0.f) ? 0u : 0x80000000u) ^ fm;
      sg.z = ((conv0_w[o*4+2] >= 0.f) ? 0u : 0x80000000u) ^ fm;
      sg.w = ((conv0_w[o*4+3] >= 0.f) ? 0u : 0x80000000u) ^ fm;
      ((uint4*)(ws + L1S))[o] = sg;
      ((float*)(ws + L1T))[o] = fsearch(dir, conv0_b[o], bn0_m[o], sc, bn0_b[o]);
    } else if (task < 160) {
      // conv block (k,o): packed taps + int threshold
      int idx = task - 32, k = idx >> 5, o = idx & 31, ko = k * 32 + o;
      float sc = bns_g[ko] / sqrtf(bns_v[ko] + 0.01f);
      int dir = sc < 0.f;
      uint fm = dir ? 0xFFFFFFFFu : 0u;
      uint wv[3];
      for (int d = 0; d < 3; ++d) {
        uint w = 0;
        for (int c = 0; c < 32; ++c)
          if (convs_w[(ko * 32 + c) * 3 + d] >= 0.f) w |= 1u << c;
        wv[d] = w ^ fm;
      }
      int T = ibs(-384, 384, dir, convs_b[ko], bns_m[ko], sc, bns_b[ko]);
      uint4 pk; pk.x = wv[0]; pk.y = wv[1]; pk.z = wv[2]; pk.w = (uint)T;
      ((uint4*)(ws + WB4))[ko] = pk;
    } else if (task < 1184) {
      // fc1 packed word (i,j), stored transposed [j][i] with 16B-chunk XOR swizzle
      int u = task - 160, i = u >> 6, j = u & 63;
      float sc = bn5_g[j] / sqrtf(bn5_v[j] + 0.01f);
      uint fm = (sc < 0.f) ? 0xFFFFFFFFu : 0u;
      uint w = 0;
      for (int c = 0; c < 32; ++c)
        if (fc1_w[j * 512 + c * 16 + i] >= 0.f) w |= 1u << c;
      int slot = j * 16 + ((((i >> 2) ^ ((j >> 3) & 3)) << 2) | (i & 3));
      ws[W1T + slot] = w ^ fm;
    } else if (task < 1248) {
      int j = task - 1184;
      float sc = bn5_g[j] / sqrtf(bn5_v[j] + 0.01f);
      int dir = sc < 0.f;
      ((int*)ws)[T5O + j] = ibs(-1025, 1025, dir, fc1_b[j], bn5_m[j], sc, bn5_b[j]);
    } else if (task < 1376) {
      // fc2 packed word [h][j]
      int u = task - 1248, h = u >> 6, j = u & 63;
      float sc = bn6_g[j] / sqrtf(bn6_v[j] + 0.01f);
      uint fm = (sc < 0.f) ? 0xFFFFFFFFu : 0u;
      uint w = 0;
      for (int c = 0; c < 32; ++c)
        if (fc2_w[j * 64 + h * 32 + c] >= 0.f) w |= 1u << c;
      ws[W2T + h * 64 + j] = w ^ fm;
    } else if (task < 1440) {
      int j = task - 1376;
      float sc = bn6_g[j] / sqrtf(bn6_v[j] + 0.01f);
      int dir = sc < 0.f;
      ((int*)ws)[T6O + j] = ibs(-65, 65, dir, fc2_b[j], bn6_m[j], sc, bn6_b[j]);
    } else if (task < 1442) {
      int h = task - 1440;
      uint w = 0;
      for (int c = 0; c < 32; ++c)
        if (fc3_w[h * 32 + c] >= 0.f) w |= 1u << c;
      ws[W3O + h] = w;
    } else {
      ((float*)ws)[FB3O] = fc3_b[0];
    }
  }
}

// 8 lanes per sample; lane l owns positions 2l, 2l+1.
__global__ __launch_bounds__(256, 6) void bnn_kernel(const float* __restrict__ x,
                                                     const uint* __restrict__ ws,
                                                     float* __restrict__ out,
                                                     int B)
{
  __shared__ uint sm[SMTOT];
  for (int i = threadIdx.x; i < SMTOT; i += 256) sm[i] = ws[W1T + i];
  __syncthreads();
  const int gt = blockIdx.x * 256 + threadIdx.x;
  const int b = gt >> 3;
  const int l = gt & 7;
  if (b >= B) return;
  const bool hasL = (l > 0), hasR = (l < 7);
  const uint mL = hasL ? ~0u : 0u;
  const uint mR = hasR ? ~0u : 0u;

  // ---- load x[b]: 4 channels x 2 owned positions (as raw bits) ----
  uint xu0[4], xu1[4];
  const float2* xp = (const float2*)(x + (size_t)b * 64 + 2 * l);
#pragma unroll
  for (int c = 0; c < 4; ++c) {
    float2 v = xp[c * 8];
    xu0[c] = __float_as_uint(v.x);
    xu1[c] = __float_as_uint(v.y);
  }

  // ---- layer 1: sign-xor products + threshold compare (descending o, add-merge) ----
  const uint4* l1s = (const uint4*)(ws + L1S);
  const float* l1t = (const float*)(ws + L1T);
  uint s0v0 = 0, s0v1 = 0;
  for (int o = 31; o >= 0; --o) {
    uint4 sg = l1s[o];
    float tf = l1t[o];
    float d0 = __fadd_rn(__fadd_rn(__fadd_rn(
                  __uint_as_float(xu0[0] ^ sg.x),
                  __uint_as_float(xu0[1] ^ sg.y)),
                  __uint_as_float(xu0[2] ^ sg.z)),
                  __uint_as_float(xu0[3] ^ sg.w));
    float d1 = __fadd_rn(__fadd_rn(__fadd_rn(
                  __uint_as_float(xu1[0] ^ sg.x),
                  __uint_as_float(xu1[1] ^ sg.y)),
                  __uint_as_float(xu1[2] ^ sg.z)),
                  __uint_as_float(xu1[3] ^ sg.w));
    s0v0 = s0v0 + s0v0 + (uint)(d0 >= tf);
    s0v1 = s0v1 + s0v1 + (uint)(d1 >= tf);
  }

  const uint s0l = (uint)__shfl_up((int)s0v1, 1);
  const uint s0r = (uint)__shfl_down((int)s0v0, 1);

  uint cur0, cur1;

  // ---- block 0: binary conv, integer threshold ----
  {
    const int M0 = hasL ? 96 : 64;
    const int M1 = hasR ? 96 : 64;
    const uint4* wb4 = (const uint4*)(ws + WB4);
    uint n0 = 0, n1 = 0;
    for (int o = 31; o >= 0; --o) {
      uint4 w = wb4[o];
      int T = (int)w.w;
      int pc0 = __popc(s0v0 ^ w.y) + __popc((s0l ^ w.x) & mL) + __popc(s0v1 ^ w.z);
      int pc1 = __popc(s0v1 ^ w.y) + __popc(s0v0 ^ w.x) + __popc((s0r ^ w.z) & mR);
      n0 = n0 + n0 + (uint)(M0 - 2 * pc0 >= T);
      n1 = n1 + n1 + (uint)(M1 - 2 * pc1 >= T);
    }
    cur0 = n0; cur1 = n1;
  }

  // ---- blocks 1..3: ternary (sign(prev)+s0) via agree masks, int thresholds ----
  for (int k = 1; k < 4; ++k) {
    const uint cl = (uint)__shfl_up((int)cur1, 1);
    const uint cr = (uint)__shfl_down((int)cur0, 1);
    const uint e0 = ~(cur0 ^ s0v0);
    const uint e1 = ~(cur1 ^ s0v1);
    const uint el = (~(cl ^ s0l)) & mL;
    const uint er = (~(cr ^ s0r)) & mR;
    const int pe0 = __popc(e0), pe1 = __popc(e1);
    const int P2_0 = 2 * (__popc(el) + pe0 + pe1);
    const int P2_1 = 2 * (pe0 + pe1 + __popc(er));
    const uint4* wb4 = (const uint4*)(ws + WB4) + k * 32;
    uint n0 = 0, n1 = 0;
    for (int o = 31; o >= 0; --o) {
      uint4 w = wb4[o];
      int T = (int)w.w;
      int pc0 = __popc((cur0 ^ w.y) & e0) + __popc((cl ^ w.x) & el)
              + __popc((cur1 ^ w.z) & e1);
      int pc1 = __popc((cur1 ^ w.y) & e1) + __popc((cur0 ^ w.x) & e0)
              + __popc((cr ^ w.z) & er);
      n0 = n0 + n0 + (uint)(P2_0 - 4 * pc0 >= T);
      n1 = n1 + n1 + (uint)(P2_1 - 4 * pc1 >= T);
    }
    cur0 = n0; cur1 = n1;
  }

  // ---- all-gather 16 position words + agree masks across the 8-lane group ----
  const int gbase = (threadIdx.x & 63) & ~7;
  uint curF[16], eF[16];
  int E = 0;
#pragma unroll
  for (int i = 0; i < 16; ++i) {
    int src = gbase + (i >> 1);
    uint cw = (uint)__shfl((i & 1) ? (int)cur1 : (int)cur0, src);
    uint sw = (uint)__shfl((i & 1) ? (int)s0v1 : (int)s0v0, src);
    curF[i] = cw;
    eF[i] = ~(cw ^ sw);
    E += __popc(eF[i]);
  }
  const int E2 = 2 * E;

  // ---- fc1: 8 outputs per lane, swizzled b128 weight reads, int thresholds ----
  const uint4* smq = (const uint4*)sm;
  const int swz = l & 3;
  uint hbits = 0;
  for (int jj = 7; jj >= 0; --jj) {
    int j = l * 8 + jj;
    int pc = 0;
#pragma unroll
    for (int c = 0; c < 4; ++c) {
      uint4 w4 = smq[j * 4 + (c ^ swz)];
      pc += __popc((curF[c*4+0] ^ w4.x) & eF[c*4+0]);
      pc += __popc((curF[c*4+1] ^ w4.y) & eF[c*4+1]);
      pc += __popc((curF[c*4+2] ^ w4.z) & eF[c*4+2]);
      pc += __popc((curF[c*4+3] ^ w4.w) & eF[c*4+3]);
    }
    hbits = hbits + hbits + (uint)(E2 - 4 * pc >= (int)sm[ST5 + j]);
  }
  uint hh = hbits << ((l & 3) * 8);
  uint h0 = (l < 4) ? hh : 0u;
  uint h1 = (l < 4) ? 0u : hh;
  h0 |= (uint)__shfl_xor((int)h0, 1); h0 |= (uint)__shfl_xor((int)h0, 2); h0 |= (uint)__shfl_xor((int)h0, 4);
  h1 |= (uint)__shfl_xor((int)h1, 1); h1 |= (uint)__shfl_xor((int)h1, 2); h1 |= (uint)__shfl_xor((int)h1, 4);

  // ---- fc2: 8 outputs per lane ----
  uint gbits = 0;
  for (int jj = 7; jj >= 0; --jj) {
    int j = l * 8 + jj;
    int pc = __popc(h0 ^ sm[SW2 + j]) + __popc(h1 ^ sm[SW2 + 64 + j]);
    gbits = gbits + gbits + (uint)(64 - 2 * pc >= (int)sm[ST6 + j]);
  }
  uint gg = gbits << ((l & 3) * 8);
  uint g0 = (l < 4) ? gg : 0u;
  uint g1 = (l < 4) ? 0u : gg;
  g0 |= (uint)__shfl_xor((int)g0, 1); g0 |= (uint)__shfl_xor((int)g0, 2); g0 |= (uint)__shfl_xor((int)g0, 4);
  g1 |= (uint)__shfl_xor((int)g1, 1); g1 |= (uint)__shfl_xor((int)g1, 2); g1 |= (uint)__shfl_xor((int)g1, 4);

  // ---- fc3 + sigmoid ----
  if (l == 0) {
    int pc = __popc(g0 ^ sm[SW3]) + __popc(g1 ^ sm[SW3 + 1]);
    float z = __fadd_rn((float)(64 - 2 * pc), __uint_as_float(sm[SFB3]));
    out[b] = 1.f / (1.f + expf(-z));
  }
}

extern "C" void kernel_launch(void* const* d_in, const int* in_sizes, int n_in,
                              void* d_out, int out_size, void* d_ws, size_t ws_size,
                              hipStream_t stream) {
  const float* x       = (const float*)d_in[0];
  const float* conv0_w = (const float*)d_in[1];
  const float* conv0_b = (const float*)d_in[2];
  const float* bn0_g   = (const float*)d_in[3];
  const float* bn0_b   = (const float*)d_in[4];
  const float* bn0_m   = (const float*)d_in[5];
  const float* bn0_v   = (const float*)d_in[6];
  const float* convs_w = (const float*)d_in[7];
  const float* convs_b = (const float*)d_in[8];
  const float* bns_g   = (const float*)d_in[9];
  const float* bns_b   = (const float*)d_in[10];
  const float* bns_m   = (const float*)d_in[11];
  const float* bns_v   = (const float*)d_in[12];
  const float* fc1_w   = (const float*)d_in[13];
  const float* fc1_b   = (const float*)d_in[14];
  const float* bn5_g   = (const float*)d_in[15];
  const float* bn5_b   = (const float*)d_in[16];
  const float* bn5_m   = (const float*)d_in[17];
  const float* bn5_v   = (const float*)d_in[18];
  const float* fc2_w   = (const float*)d_in[19];
  const float* fc2_b   = (const float*)d_in[20];
  const float* bn6_g   = (const float*)d_in[21];
  const float* bn6_b   = (const float*)d_in[22];
  const float* bn6_m   = (const float*)d_in[23];
  const float* bn6_v   = (const float*)d_in[24];
  const float* fc3_w   = (const float*)d_in[25];
  const float* fc3_b   = (const float*)d_in[26];
  uint* ws = (uint*)d_ws;

  hipLaunchKernelGGL(prep_kernel, dim3(6), dim3(256), 0, stream,
                     conv0_w, conv0_b, bn0_g, bn0_b, bn0_m, bn0_v,
                     convs_w, convs_b, bns_g, bns_b, bns_m, bns_v,
                     fc1_w, fc1_b, bn5_g, bn5_b, bn5_m, bn5_v,
                     fc2_w, fc2_b, bn6_g, bn6_b, bn6_m, bn6_v,
                     fc3_w, fc3_b, ws);

  const int B = in_sizes[0] / 64;   // 65536
  const int threads = B * 8;        // 8 lanes per sample
  hipLaunchKernelGGL(bnn_kernel, dim3((threads + 255) / 256), dim3(256), 0, stream,
                     x, ws, (float*)d_out, B);
}

// Round 5
// 179.997 us; speedup vs baseline: 1.2338x; 1.0110x over previous
//
#include <hip/hip_runtime.h>
#include <hip/hip_bf16.h>
#include <math.h>

typedef unsigned int uint;

// ---- ws layout (uint word offsets) ----
#define WB4   0      // uint4[4*32]: per (k,o): {wa,wb,wc,(uint)T}  words 0..511
#define L1S   512    // uint4[32]: layer1 sign masks (0 / 0x80000000 per input ch)
#define L1T   640    // float[32]: layer1 thresholds
#define W1T   672    // uint[64*16]: fc1 packed, transposed+chunk-swizzled [j][i]
#define T5O   1696   // int[64]
#define W2T   1760   // uint[2*64]: fc2 packed, [h][j]
#define T6O   1888   // int[64]
#define W3O   1952   // uint[2]
#define FB3O  1954   // float fc3_b
#define TOTW  1955

// exact replication of the reference BN chain: r = ((v+cb)-m)*sc + b
__device__ __forceinline__ float bnr(float v, float cb, float m, float sc, float b) {
  return __fadd_rn(__fmul_rn(__fsub_rn(__fadd_rn(v, cb), m), sc), b);
}

// min integer c in [lo,hi] with bnr(dir ? -c : c) >= 0 (monotone), else hi+1
__device__ __forceinline__ int ibs(int lo, int hi, int dir,
                                   float cb, float m, float sc, float b) {
  int ans = hi + 1;
  while (lo <= hi) {
    int mid = lo + ((hi - lo) >> 1);
    float vf = (float)(dir ? -mid : mid);
    if (bnr(vf, cb, m, sc, b) >= 0.f) { ans = mid; hi = mid - 1; }
    else lo = mid + 1;
  }
  return ans;
}

// sortable-key <-> float
__device__ __forceinline__ float key2f(uint k) {
  return __uint_as_float((k & 0x80000000u) ? (k ^ 0x80000000u) : ~k);
}

// minimal float d' (ordered) with bnr(dir ? -d' : d') >= 0  (monotone chain)
__device__ __forceinline__ float fsearch(int dir, float cb, float m, float sc, float b) {
  uint lo = 0x00800000u;   // key(-FLT_MAX)
  uint hi = 0xFF7FFFFFu;   // key(+FLT_MAX)
  float fhi = key2f(hi);
  if (!(bnr(dir ? -fhi : fhi, cb, m, sc, b) >= 0.f))
    return __uint_as_float(0x7F800000u);  // +inf : never true
  while (lo < hi) {
    uint mid = lo + ((hi - lo) >> 1);
    float fm = key2f(mid);
    if (bnr(dir ? -fm : fm, cb, m, sc, b) >= 0.f) hi = mid; else lo = mid + 1;
  }
  return key2f(lo);
}

__global__ void prep_kernel(
    const float* __restrict__ conv0_w, const float* __restrict__ conv0_b,
    const float* __restrict__ bn0_g, const float* __restrict__ bn0_b,
    const float* __restrict__ bn0_m, const float* __restrict__ bn0_v,
    const float* __restrict__ convs_w, const float* __restrict__ convs_b,
    const float* __restrict__ bns_g, const float* __restrict__ bns_b,
    const float* __restrict__ bns_m, const float* __restrict__ bns_v,
    const float* __restrict__ fc1_w, const float* __restrict__ fc1_b,
    const float* __restrict__ bn5_g, const float* __restrict__ bn5_b,
    const float* __restrict__ bn5_m, const float* __restrict__ bn5_v,
    const float* __restrict__ fc2_w, const float* __restrict__ fc2_b,
    const float* __restrict__ bn6_g, const float* __restrict__ bn6_b,
    const float* __restrict__ bn6_m, const float* __restrict__ bn6_v,
    const float* __restrict__ fc3_w, const float* __restrict__ fc3_b,
    uint* __restrict__ ws)
{
  const int t0 = blockIdx.x * blockDim.x + threadIdx.x;
  const int NT = gridDim.x * blockDim.x;
  for (int task = t0; task < 1443; task += NT) {
    if (task < 32) {
      // layer1 channel o: sign masks + float threshold
      int o = task;
      float sc = bn0_g[o] / sqrtf(bn0_v[o] + 0.01f);
      int dir = sc < 0.f;
      uint fm = dir ? 0x80000000u : 0u;
      uint4 sg;
      sg.x = ((conv0_w[o*4+0] >= 0.f) ? 0u : 0x80000000u) ^ fm;
      sg.y = ((conv0_w[o*4+1] >= 0.f) ? 0u : 0x80000000u) ^ fm;
      sg.z = ((conv0_w[o*4+2] >= 0.f) ? 0u : 0x80000000u) ^ fm;
      sg.w = ((conv0_w[o*4+3] >= 0.f) ? 0u : 0x80000000u) ^ fm;
      ((uint4*)(ws + L1S))[o] = sg;
      ((float*)(ws + L1T))[o] = fsearch(dir, conv0_b[o], bn0_m[o], sc, bn0_b[o]);
    } else if (task < 160) {
      // conv block (k,o): packed taps + int threshold
      int idx = task - 32, k = idx >> 5, o = idx & 31, ko = k * 32 + o;
      float sc = bns_g[ko] / sqrtf(bns_v[ko] + 0.01f);
      int dir = sc < 0.f;
      uint fm = dir ? 0xFFFFFFFFu : 0u;
      uint wv[3];
      for (int d = 0; d < 3; ++d) {
        uint w = 0;
        for (int c = 0; c < 32; ++c)
          if (convs_w[(ko * 32 + c) * 3 + d] >= 0.f) w |= 1u << c;
        wv[d] = w ^ fm;
      }
      int T = ibs(-384, 384, dir, convs_b[ko], bns_m[ko], sc, bns_b[ko]);
      uint4 pk; pk.x = wv[0]; pk.y = wv[1]; pk.z = wv[2]; pk.w = (uint)T;
      ((uint4*)(ws + WB4))[ko] = pk;
    } else if (task < 1184) {
      // fc1 packed word (i,j), stored transposed [j][i] with 16B-chunk XOR swizzle
      int u = task - 160, i = u >> 6, j = u & 63;
      float sc = bn5_g[j] / sqrtf(bn5_v[j] + 0.01f);
      uint fm = (sc < 0.f) ? 0xFFFFFFFFu : 0u;
      uint w = 0;
      for (int c = 0; c < 32; ++c)
        if (fc1_w[j * 512 + c * 16 + i] >= 0.f) w |= 1u << c;
      int slot = j * 16 + ((((i >> 2) ^ ((j >> 3) & 3)) << 2) | (i & 3));
      ws[W1T + slot] = w ^ fm;
    } else if (task < 1248) {
      int j = task - 1184;
      float sc = bn5_g[j] / sqrtf(bn5_v[j] + 0.01f);
      int dir = sc < 0.f;
      ((int*)ws)[T5O + j] = ibs(-1025, 1025, dir, fc1_b[j], bn5_m[j], sc, bn5_b[j]);
    } else if (task < 1376) {
      // fc2 packed word [h][j]
      int u = task - 1248, h = u >> 6, j = u & 63;
      float sc = bn6_g[j] / sqrtf(bn6_v[j] + 0.01f);
      uint fm = (sc < 0.f) ? 0xFFFFFFFFu : 0u;
      uint w = 0;
      for (int c = 0; c < 32; ++c)
        if (fc2_w[j * 64 + h * 32 + c] >= 0.f) w |= 1u << c;
      ws[W2T + h * 64 + j] = w ^ fm;
    } else if (task < 1440) {
      int j = task - 1376;
      float sc = bn6_g[j] / sqrtf(bn6_v[j] + 0.01f);
      int dir = sc < 0.f;
      ((int*)ws)[T6O + j] = ibs(-65, 65, dir, fc2_b[j], bn6_m[j], sc, bn6_b[j]);
    } else if (task < 1442) {
      int h = task - 1440;
      uint w = 0;
      for (int c = 0; c < 32; ++c)
        if (fc3_w[h * 32 + c] >= 0.f) w |= 1u << c;
      ws[W3O + h] = w;
    } else {
      ((float*)ws)[FB3O] = fc3_b[0];
    }
  }
}

// broadcast value from lane ((lane & ~7) | g) within each 8-lane group
#define SWZB(v, g) ((uint)__builtin_amdgcn_ds_swizzle((int)(v), ((g) << 5) | 0x18))

// 8 lanes per sample; lane l owns positions 2l, 2l+1.
__global__ __launch_bounds__(256, 8) void bnn_kernel(const float* __restrict__ x,
                                                     const uint* __restrict__ ws,
                                                     float* __restrict__ out,
                                                     int B)
{
  __shared__ __align__(16) uint sm[TOTW];
  const int gt = blockIdx.x * 256 + threadIdx.x;
  const int b = gt >> 3;
  const int l = gt & 7;

  // issue x loads early (hide global latency under the LDS fill)
  uint xu0[4], xu1[4];
  if (b < B) {
    const float2* xp = (const float2*)(x + (size_t)b * 64 + 2 * l);
#pragma unroll
    for (int c = 0; c < 4; ++c) {
      float2 v = xp[c * 8];
      xu0[c] = __float_as_uint(v.x);
      xu1[c] = __float_as_uint(v.y);
    }
  }

  // mirror ALL tables into LDS -> every table access is ds_read with imm offset
  for (int i = threadIdx.x; i < TOTW; i += 256) sm[i] = ws[i];
  __syncthreads();
  if (b >= B) return;

  const bool hasL = (l > 0), hasR = (l < 7);
  const uint mL = hasL ? ~0u : 0u;
  const uint mR = hasR ? ~0u : 0u;

  // ---- layer 1: sign-xor products + threshold compare (descending o, add-merge) ----
  const uint4* l1s = (const uint4*)(sm + L1S);
  const float* l1t = (const float*)(sm + L1T);
  uint s0v0 = 0, s0v1 = 0;
#pragma unroll
  for (int o = 31; o >= 0; --o) {
    uint4 sg = l1s[o];
    float tf = l1t[o];
    float d0 = __fadd_rn(__fadd_rn(__fadd_rn(
                  __uint_as_float(xu0[0] ^ sg.x),
                  __uint_as_float(xu0[1] ^ sg.y)),
                  __uint_as_float(xu0[2] ^ sg.z)),
                  __uint_as_float(xu0[3] ^ sg.w));
    float d1 = __fadd_rn(__fadd_rn(__fadd_rn(
                  __uint_as_float(xu1[0] ^ sg.x),
                  __uint_as_float(xu1[1] ^ sg.y)),
                  __uint_as_float(xu1[2] ^ sg.z)),
                  __uint_as_float(xu1[3] ^ sg.w));
    s0v0 = s0v0 + s0v0 + (uint)(d0 >= tf);
    s0v1 = s0v1 + s0v1 + (uint)(d1 >= tf);
  }

  const uint s0l = (uint)__shfl_up((int)s0v1, 1);
  const uint s0r = (uint)__shfl_down((int)s0v0, 1);

  uint cur0, cur1;

  // ---- block 0: binary conv, integer threshold ----
  {
    const int M0 = hasL ? 96 : 64;
    const int M1 = hasR ? 96 : 64;
    const uint4* wb4 = (const uint4*)(sm + WB4);
    uint n0 = 0, n1 = 0;
#pragma unroll
    for (int o = 31; o >= 0; --o) {
      uint4 w = wb4[o];
      int T = (int)w.w;
      int pc0 = __popc(s0v0 ^ w.y) + __popc((s0l ^ w.x) & mL) + __popc(s0v1 ^ w.z);
      int pc1 = __popc(s0v1 ^ w.y) + __popc(s0v0 ^ w.x) + __popc((s0r ^ w.z) & mR);
      n0 = n0 + n0 + (uint)(M0 - 2 * pc0 >= T);
      n1 = n1 + n1 + (uint)(M1 - 2 * pc1 >= T);
    }
    cur0 = n0; cur1 = n1;
  }

  // ---- blocks 1..3: ternary (sign(prev)+s0) via agree masks, int thresholds ----
  for (int k = 1; k < 4; ++k) {
    const uint cl = (uint)__shfl_up((int)cur1, 1);
    const uint cr = (uint)__shfl_down((int)cur0, 1);
    const uint e0 = ~(cur0 ^ s0v0);
    const uint e1 = ~(cur1 ^ s0v1);
    const uint el = (~(cl ^ s0l)) & mL;
    const uint er = (~(cr ^ s0r)) & mR;
    const int pe0 = __popc(e0), pe1 = __popc(e1);
    const int P2_0 = 2 * (__popc(el) + pe0 + pe1);
    const int P2_1 = 2 * (pe0 + pe1 + __popc(er));
    const uint4* wb4 = (const uint4*)(sm + WB4) + k * 32;
    uint n0 = 0, n1 = 0;
#pragma unroll
    for (int o = 31; o >= 0; --o) {
      uint4 w = wb4[o];
      int T = (int)w.w;
      int pc0 = __popc((cur0 ^ w.y) & e0) + __popc((cl ^ w.x) & el)
              + __popc((cur1 ^ w.z) & e1);
      int pc1 = __popc((cur1 ^ w.y) & e1) + __popc((cur0 ^ w.x) & e0)
              + __popc((cr ^ w.z) & er);
      n0 = n0 + n0 + (uint)(P2_0 - 4 * pc0 >= T);
      n1 = n1 + n1 + (uint)(P2_1 - 4 * pc1 >= T);
    }
    cur0 = n0; cur1 = n1;
  }

  // ---- all-gather 16 position words + agree masks via ds_swizzle broadcasts ----
  uint curF[16], eF[16];
  int E = 0;
#define GAT(g) { \
    uint cw0 = SWZB(cur0, g), cw1 = SWZB(cur1, g); \
    uint sw0 = SWZB(s0v0, g), sw1 = SWZB(s0v1, g); \
    curF[2*(g)]   = cw0; eF[2*(g)]   = ~(cw0 ^ sw0); \
    curF[2*(g)+1] = cw1; eF[2*(g)+1] = ~(cw1 ^ sw1); \
    E += __popc(eF[2*(g)]) + __popc(eF[2*(g)+1]); }
  GAT(0) GAT(1) GAT(2) GAT(3) GAT(4) GAT(5) GAT(6) GAT(7)
#undef GAT
  const int E2 = 2 * E;

  // ---- fc1: 8 outputs per lane, swizzled b128 reads via 4 fixed chunk bases ----
  const int swz = l & 3;
  const uint4* pA = (const uint4*)(sm + W1T + l * 128 + ((0 ^ swz) << 2));
  const uint4* pB = (const uint4*)(sm + W1T + l * 128 + ((1 ^ swz) << 2));
  const uint4* pC = (const uint4*)(sm + W1T + l * 128 + ((2 ^ swz) << 2));
  const uint4* pD = (const uint4*)(sm + W1T + l * 128 + ((3 ^ swz) << 2));
  const int jb = l * 8;
  uint hbits = 0;
#pragma unroll
  for (int jj = 7; jj >= 0; --jj) {
    uint4 wA = pA[jj * 4];
    uint4 wB = pB[jj * 4];
    uint4 wC = pC[jj * 4];
    uint4 wD = pD[jj * 4];
    int pc = 0;
    pc += __popc((curF[0]  ^ wA.x) & eF[0]);
    pc += __popc((curF[1]  ^ wA.y) & eF[1]);
    pc += __popc((curF[2]  ^ wA.z) & eF[2]);
    pc += __popc((curF[3]  ^ wA.w) & eF[3]);
    pc += __popc((curF[4]  ^ wB.x) & eF[4]);
    pc += __popc((curF[5]  ^ wB.y) & eF[5]);
    pc += __popc((curF[6]  ^ wB.z) & eF[6]);
    pc += __popc((curF[7]  ^ wB.w) & eF[7]);
    pc += __popc((curF[8]  ^ wC.x) & eF[8]);
    pc += __popc((curF[9]  ^ wC.y) & eF[9]);
    pc += __popc((curF[10] ^ wC.z) & eF[10]);
    pc += __popc((curF[11] ^ wC.w) & eF[11]);
    pc += __popc((curF[12] ^ wD.x) & eF[12]);
    pc += __popc((curF[13] ^ wD.y) & eF[13]);
    pc += __popc((curF[14] ^ wD.z) & eF[14]);
    pc += __popc((curF[15] ^ wD.w) & eF[15]);
    hbits = hbits + hbits + (uint)(E2 - 4 * pc >= (int)sm[T5O + jb + jj]);
  }
  uint hh = hbits << ((l & 3) * 8);
  uint h0 = (l < 4) ? hh : 0u;
  uint h1 = (l < 4) ? 0u : hh;
  h0 |= (uint)__shfl_xor((int)h0, 1); h0 |= (uint)__shfl_xor((int)h0, 2); h0 |= (uint)__shfl_xor((int)h0, 4);
  h1 |= (uint)__shfl_xor((int)h1, 1); h1 |= (uint)__shfl_xor((int)h1, 2); h1 |= (uint)__shfl_xor((int)h1, 4);

  // ---- fc2: 8 outputs per lane ----
  uint gbits = 0;
#pragma unroll
  for (int jj = 7; jj >= 0; --jj) {
    int pc = __popc(h0 ^ sm[W2T + jb + jj]) + __popc(h1 ^ sm[W2T + 64 + jb + jj]);
    gbits = gbits + gbits + (uint)(64 - 2 * pc >= (int)sm[T6O + jb + jj]);
  }
  uint gg = gbits << ((l & 3) * 8);
  uint g0 = (l < 4) ? gg : 0u;
  uint g1 = (l < 4) ? 0u : gg;
  g0 |= (uint)__shfl_xor((int)g0, 1); g0 |= (uint)__shfl_xor((int)g0, 2); g0 |= (uint)__shfl_xor((int)g0, 4);
  g1 |= (uint)__shfl_xor((int)g1, 1); g1 |= (uint)__shfl_xor((int)g1, 2); g1 |= (uint)__shfl_xor((int)g1, 4);

  // ---- fc3 + sigmoid ----
  if (l == 0) {
    int pc = __popc(g0 ^ sm[W3O]) + __popc(g1 ^ sm[W3O + 1]);
    float z = __fadd_rn((float)(64 - 2 * pc), __uint_as_float(sm[FB3O]));
    out[b] = 1.f / (1.f + expf(-z));
  }
}

extern "C" void kernel_launch(void* const* d_in, const int* in_sizes, int n_in,
                              void* d_out, int out_size, void* d_ws, size_t ws_size,
                              hipStream_t stream) {
  const float* x       = (const float*)d_in[0];
  const float* conv0_w = (const float*)d_in[1];
  const float* conv0_b = (const float*)d_in[2];
  const float* bn0_g   = (const float*)d_in[3];
  const float* bn0_b   = (const float*)d_in[4];
  const float* bn0_m   = (const float*)d_in[5];
  const float* bn0_v   = (const float*)d_in[6];
  const float* convs_w = (const float*)d_in[7];
  const float* convs_b = (const float*)d_in[8];
  const float* bns_g   = (const float*)d_in[9];
  const float* bns_b   = (const float*)d_in[10];
  const float* bns_m   = (const float*)d_in[11];
  const float* bns_v   = (const float*)d_in[12];
  const float* fc1_w   = (const float*)d_in[13];
  const float* fc1_b   = (const float*)d_in[14];
  const float* bn5_g   = (const float*)d_in[15];
  const float* bn5_b   = (const float*)d_in[16];
  const float* bn5_m   = (const float*)d_in[17];
  const float* bn5_v   = (const float*)d_in[18];
  const float* fc2_w   = (const float*)d_in[19];
  const float* fc2_b   = (const float*)d_in[20];
  const float* bn6_g   = (const float*)d_in[21];
  const float* bn6_b   = (const float*)d_in[22];
  const float* bn6_m   = (const float*)d_in[23];
  const float* bn6_v   = (const float*)d_in[24];
  const float* fc3_w   = (const float*)d_in[25];
  const float* fc3_b   = (const float*)d_in[26];
  uint* ws = (uint*)d_ws;

  hipLaunchKernelGGL(prep_kernel, dim3(6), dim3(256), 0, stream,
                     conv0_w, conv0_b, bn0_g, bn0_b, bn0_m, bn0_v,
                     convs_w, convs_b, bns_g, bns_b, bns_m, bns_v,
                     fc1_w, fc1_b, bn5_g, bn5_b, bn5_m, bn5_v,
                     fc2_w, fc2_b, bn6_g, bn6_b, bn6_m, bn6_v,
                     fc3_w, fc3_b, ws);

  const int B = in_sizes[0] / 64;   // 65536
  const int threads = B * 8;        // 8 lanes per sample
  hipLaunchKernelGGL(bnn_kernel, dim3((threads + 255) / 256), dim3(256), 0, stream,
                     x, ws, (float*)d_out, B);
}

// Round 6
// 172.112 us; speedup vs baseline: 1.2904x; 1.0458x over previous
//
#include <hip/hip_runtime.h>
#include <hip/hip_bf16.h>
#include <math.h>

typedef unsigned int uint;
typedef float vf2 __attribute__((ext_vector_type(2)));

// ---- ws layout (uint word offsets) ----
#define WB4   0      // uint4[4*32]: per (k,o): {wa,wb,wc,(uint)T(k==0) or ceil(T/2)(k>0)}
#define L1S   512    // uint4[32]: layer1 sign masks
#define L1T   640    // float[32]: layer1 thresholds
#define W1T   672    // uint[64*16]: fc1 packed, transposed+chunk-swizzled [j][i]
#define T5O   1696   // int[64]: ceil(T/2)
#define W2T   1760   // uint[2*64]: fc2 packed, [h][j]
#define T6O   1888   // int[64]: raw T
#define W3O   1952   // uint[2]
#define FB3O  1954   // float fc3_b
#define TOTW  1955

// LDS mirror covers [W1T, TOTW)  (lane-dependent tables only)
#define ST5   (T5O - W1T)
#define SW2   (W2T - W1T)
#define ST6   (T6O - W1T)
#define SW3   (W3O - W1T)
#define SFB3  (FB3O - W1T)
#define SMTOT (TOTW - W1T)

// exact replication of the reference BN chain: r = ((v+cb)-m)*sc + b
__device__ __forceinline__ float bnr(float v, float cb, float m, float sc, float b) {
  return __fadd_rn(__fmul_rn(__fsub_rn(__fadd_rn(v, cb), m), sc), b);
}

// min integer c in [lo,hi] with bnr(dir ? -c : c) >= 0 (monotone), else hi+1
__device__ __forceinline__ int ibs(int lo, int hi, int dir,
                                   float cb, float m, float sc, float b) {
  int ans = hi + 1;
  while (lo <= hi) {
    int mid = lo + ((hi - lo) >> 1);
    float vf = (float)(dir ? -mid : mid);
    if (bnr(vf, cb, m, sc, b) >= 0.f) { ans = mid; hi = mid - 1; }
    else lo = mid + 1;
  }
  return ans;
}

// sortable-key <-> float
__device__ __forceinline__ float key2f(uint k) {
  return __uint_as_float((k & 0x80000000u) ? (k ^ 0x80000000u) : ~k);
}

// minimal float d' (ordered) with bnr(dir ? -d' : d') >= 0  (monotone chain)
__device__ __forceinline__ float fsearch(int dir, float cb, float m, float sc, float b) {
  uint lo = 0x00800000u;   // key(-FLT_MAX)
  uint hi = 0xFF7FFFFFu;   // key(+FLT_MAX)
  float fhi = key2f(hi);
  if (!(bnr(dir ? -fhi : fhi, cb, m, sc, b) >= 0.f))
    return __uint_as_float(0x7F800000u);  // +inf : never true
  while (lo < hi) {
    uint mid = lo + ((hi - lo) >> 1);
    float fm = key2f(mid);
    if (bnr(dir ? -fm : fm, cb, m, sc, b) >= 0.f) hi = mid; else lo = mid + 1;
  }
  return key2f(lo);
}

__global__ void prep_kernel(
    const float* __restrict__ conv0_w, const float* __restrict__ conv0_b,
    const float* __restrict__ bn0_g, const float* __restrict__ bn0_b,
    const float* __restrict__ bn0_m, const float* __restrict__ bn0_v,
    const float* __restrict__ convs_w, const float* __restrict__ convs_b,
    const float* __restrict__ bns_g, const float* __restrict__ bns_b,
    const float* __restrict__ bns_m, const float* __restrict__ bns_v,
    const float* __restrict__ fc1_w, const float* __restrict__ fc1_b,
    const float* __restrict__ bn5_g, const float* __restrict__ bn5_b,
    const float* __restrict__ bn5_m, const float* __restrict__ bn5_v,
    const float* __restrict__ fc2_w, const float* __restrict__ fc2_b,
    const float* __restrict__ bn6_g, const float* __restrict__ bn6_b,
    const float* __restrict__ bn6_m, const float* __restrict__ bn6_v,
    const float* __restrict__ fc3_w, const float* __restrict__ fc3_b,
    uint* __restrict__ ws)
{
  const int t0 = blockIdx.x * blockDim.x + threadIdx.x;
  const int NT = gridDim.x * blockDim.x;
  for (int task = t0; task < 1443; task += NT) {
    if (task < 32) {
      // layer1 channel o: sign masks + float threshold
      int o = task;
      float sc = bn0_g[o] / sqrtf(bn0_v[o] + 0.01f);
      int dir = sc < 0.f;
      uint fm = dir ? 0x80000000u : 0u;
      uint4 sg;
      sg.x = ((conv0_w[o*4+0] >= 0.f) ? 0u : 0x80000000u) ^ fm;
      sg.y = ((conv0_w[o*4+1] >= 0.f) ? 0u : 0x80000000u) ^ fm;
      sg.z = ((conv0_w[o*4+2] >= 0.f) ? 0u : 0x80000000u) ^ fm;
      sg.w = ((conv0_w[o*4+3] >= 0.f) ? 0u : 0x80000000u) ^ fm;
      ((uint4*)(ws + L1S))[o] = sg;
      ((float*)(ws + L1T))[o] = fsearch(dir, conv0_b[o], bn0_m[o], sc, bn0_b[o]);
    } else if (task < 160) {
      // conv block (k,o): packed taps + int threshold
      int idx = task - 32, k = idx >> 5, o = idx & 31, ko = k * 32 + o;
      float sc = bns_g[ko] / sqrtf(bns_v[ko] + 0.01f);
      int dir = sc < 0.f;
      uint fm = dir ? 0xFFFFFFFFu : 0u;
      uint wv[3];
      for (int d = 0; d < 3; ++d) {
        uint w = 0;
        for (int c = 0; c < 32; ++c)
          if (convs_w[(ko * 32 + c) * 3 + d] >= 0.f) w |= 1u << c;
        wv[d] = w ^ fm;
      }
      int T = ibs(-384, 384, dir, convs_b[ko], bns_m[ko], sc, bns_b[ko]);
      // k==0 compares M - 2*pc >= T (raw T); k>0 compares S - 2*pc >= ceil(T/2)
      int Ts = (k == 0) ? T : ((T + 1) >> 1);
      uint4 pk; pk.x = wv[0]; pk.y = wv[1]; pk.z = wv[2]; pk.w = (uint)Ts;
      ((uint4*)(ws + WB4))[ko] = pk;
    } else if (task < 1184) {
      // fc1 packed word (i,j), stored transposed [j][i] with 16B-chunk XOR swizzle
      int u = task - 160, i = u >> 6, j = u & 63;
      float sc = bn5_g[j] / sqrtf(bn5_v[j] + 0.01f);
      uint fm = (sc < 0.f) ? 0xFFFFFFFFu : 0u;
      uint w = 0;
      for (int c = 0; c < 32; ++c)
        if (fc1_w[j * 512 + c * 16 + i] >= 0.f) w |= 1u << c;
      int slot = j * 16 + ((((i >> 2) ^ ((j >> 3) & 3)) << 2) | (i & 3));
      ws[W1T + slot] = w ^ fm;
    } else if (task < 1248) {
      int j = task - 1184;
      float sc = bn5_g[j] / sqrtf(bn5_v[j] + 0.01f);
      int dir = sc < 0.f;
      int T = ibs(-1025, 1025, dir, fc1_b[j], bn5_m[j], sc, bn5_b[j]);
      ((int*)ws)[T5O + j] = (T + 1) >> 1;   // cond: (E - 2*pc) >= ceil(T/2)
    } else if (task < 1376) {
      // fc2 packed word [h][j]
      int u = task - 1248, h = u >> 6, j = u & 63;
      float sc = bn6_g[j] / sqrtf(bn6_v[j] + 0.01f);
      uint fm = (sc < 0.f) ? 0xFFFFFFFFu : 0u;
      uint w = 0;
      for (int c = 0; c < 32; ++c)
        if (fc2_w[j * 64 + h * 32 + c] >= 0.f) w |= 1u << c;
      ws[W2T + h * 64 + j] = w ^ fm;
    } else if (task < 1440) {
      int j = task - 1376;
      float sc = bn6_g[j] / sqrtf(bn6_v[j] + 0.01f);
      int dir = sc < 0.f;
      ((int*)ws)[T6O + j] = ibs(-65, 65, dir, fc2_b[j], bn6_m[j], sc, bn6_b[j]);
    } else if (task < 1442) {
      int h = task - 1440;
      uint w = 0;
      for (int c = 0; c < 32; ++c)
        if (fc3_w[h * 32 + c] >= 0.f) w |= 1u << c;
      ws[W3O + h] = w;
    } else {
      ((float*)ws)[FB3O] = fc3_b[0];
    }
  }
}

// d = a*(-2) + c, exact for |a| < 2^23 (pc <= 512 here)
__device__ __forceinline__ int madm2(int a, int c) {
  int d;
  asm("v_mad_i32_i24 %0, %1, -2, %2" : "=v"(d) : "v"(a), "v"(c));
  return d;
}

// broadcast value from lane ((lane & ~7) | g) within each 8-lane group
#define SWZB(v, g) ((uint)__builtin_amdgcn_ds_swizzle((int)(v), ((g) << 5) | 0x18))

// one ternary residual conv layer (inputs cur+s0), fully unrolled
__device__ __forceinline__ void tern_layer(const uint* __restrict__ ws, int koff,
                                           uint& cur0, uint& cur1,
                                           uint s0v0, uint s0v1, uint s0l, uint s0r,
                                           uint mL, uint mR)
{
  const uint cl = (uint)__shfl_up((int)cur1, 1);
  const uint cr = (uint)__shfl_down((int)cur0, 1);
  const uint e0 = ~(cur0 ^ s0v0);
  const uint e1 = ~(cur1 ^ s0v1);
  const uint el = (~(cl ^ s0l)) & mL;
  const uint er = (~(cr ^ s0r)) & mR;
  const int pe0 = __popc(e0), pe1 = __popc(e1);
  const int S0s = __popc(el) + pe0 + pe1;   // active counts (un-doubled)
  const int S1s = pe0 + pe1 + __popc(er);
  const uint4* __restrict__ wb = (const uint4*)(ws + WB4) + koff;
  uint n0 = 0, n1 = 0;
#pragma unroll
  for (int o = 31; o >= 0; --o) {
    uint4 w = wb[o];
    int Th = (int)w.w;  // ceil(T/2)
    int pc0 = __popc((cur0 ^ w.y) & e0) + (__popc((cl ^ w.x) & el)
            + __popc((cur1 ^ w.z) & e1));
    int pc1 = __popc((cur1 ^ w.y) & e1) + (__popc((cur0 ^ w.x) & e0)
            + __popc((cr ^ w.z) & er));
    n0 = n0 + n0 + (uint)(madm2(pc0, S0s) >= Th);
    n1 = n1 + n1 + (uint)(madm2(pc1, S1s) >= Th);
  }
  cur0 = n0; cur1 = n1;
}

// 8 lanes per sample; lane l owns positions 2l, 2l+1.
__global__ __launch_bounds__(256, 4) void bnn_kernel(const float* __restrict__ x,
                                                     const uint* __restrict__ ws,
                                                     float* __restrict__ out,
                                                     int B)
{
  __shared__ __align__(16) uint sm[SMTOT];
  const int gt = blockIdx.x * 256 + threadIdx.x;
  const int b = gt >> 3;
  const int l = gt & 7;

  // issue x loads early (hide global latency under the LDS fill)
  uint xu0[4], xu1[4];
  if (b < B) {
    const float2* xp = (const float2*)(x + (size_t)b * 64 + 2 * l);
#pragma unroll
    for (int c = 0; c < 4; ++c) {
      float2 v = xp[c * 8];
      xu0[c] = __float_as_uint(v.x);
      xu1[c] = __float_as_uint(v.y);
    }
  }

  // mirror lane-dependent tables into LDS
  for (int i = threadIdx.x; i < SMTOT; i += 256) sm[i] = ws[W1T + i];
  __syncthreads();
  if (b >= B) return;

  const bool hasL = (l > 0), hasR = (l < 7);
  const uint mL = hasL ? ~0u : 0u;
  const uint mR = hasR ? ~0u : 0u;

  // ---- layer 1: sign-xor products, packed f32 adds, threshold compare ----
  const uint4* __restrict__ l1s = (const uint4*)(ws + L1S);
  const float* __restrict__ l1t = (const float*)(ws + L1T);
  uint s0v0 = 0, s0v1 = 0;
#pragma unroll
  for (int o = 31; o >= 0; --o) {
    uint4 sg = l1s[o];
    float tf = l1t[o];
    vf2 v0 = { __uint_as_float(xu0[0] ^ sg.x), __uint_as_float(xu1[0] ^ sg.x) };
    vf2 v1 = { __uint_as_float(xu0[1] ^ sg.y), __uint_as_float(xu1[1] ^ sg.y) };
    vf2 v2 = { __uint_as_float(xu0[2] ^ sg.z), __uint_as_float(xu1[2] ^ sg.z) };
    vf2 v3 = { __uint_as_float(xu0[3] ^ sg.w), __uint_as_float(xu1[3] ^ sg.w) };
    vf2 d = ((v0 + v1) + v2) + v3;   // per-lane order == reference; no fast-math
    s0v0 = s0v0 + s0v0 + (uint)(d.x >= tf);
    s0v1 = s0v1 + s0v1 + (uint)(d.y >= tf);
  }

  const uint s0l = (uint)__shfl_up((int)s0v1, 1);
  const uint s0r = (uint)__shfl_down((int)s0v0, 1);

  uint cur0, cur1;

  // ---- block 0: binary conv, integer threshold (raw T) ----
  {
    const int M0v = hasL ? 96 : 64;
    const int M1v = hasR ? 96 : 64;
    const uint4* __restrict__ wb = (const uint4*)(ws + WB4);
    uint n0 = 0, n1 = 0;
#pragma unroll
    for (int o = 31; o >= 0; --o) {
      uint4 w = wb[o];
      int T = (int)w.w;
      int pc0 = __popc(s0v0 ^ w.y) + (__popc((s0l ^ w.x) & mL) + __popc(s0v1 ^ w.z));
      int pc1 = __popc(s0v1 ^ w.y) + (__popc(s0v0 ^ w.x) + __popc((s0r ^ w.z) & mR));
      n0 = n0 + n0 + (uint)(madm2(pc0, M0v) >= T);
      n1 = n1 + n1 + (uint)(madm2(pc1, M1v) >= T);
    }
    cur0 = n0; cur1 = n1;
  }

  // ---- blocks 1..3 (manually unrolled) ----
  tern_layer(ws, 32, cur0, cur1, s0v0, s0v1, s0l, s0r, mL, mR);
  tern_layer(ws, 64, cur0, cur1, s0v0, s0v1, s0l, s0r, mL, mR);
  tern_layer(ws, 96, cur0, cur1, s0v0, s0v1, s0l, s0r, mL, mR);

  // ---- final agree masks at source lane; E via 3-step tree ----
  const uint e0f = ~(cur0 ^ s0v0);
  const uint e1f = ~(cur1 ^ s0v1);
  int le = __popc(e0f) + __popc(e1f);
  le += __shfl_xor(le, 1); le += __shfl_xor(le, 2); le += __shfl_xor(le, 4);
  const int E = le;   // total active over the sample (<= 512)

  // ---- all-gather 16 position words + e-masks via ds_swizzle broadcasts ----
  uint curF[16], eF[16];
#define GAT(g) { \
    curF[2*(g)]   = SWZB(cur0, g); curF[2*(g)+1] = SWZB(cur1, g); \
    eF[2*(g)]     = SWZB(e0f, g);  eF[2*(g)+1]   = SWZB(e1f, g); }
  GAT(0) GAT(1) GAT(2) GAT(3) GAT(4) GAT(5) GAT(6) GAT(7)
#undef GAT

  // ---- fc1: 8 outputs per lane, swizzled b128 reads via 4 fixed chunk bases ----
  const int swz = l & 3;
  const uint4* pA = (const uint4*)(sm + l * 128 + ((0 ^ swz) << 2));
  const uint4* pB = (const uint4*)(sm + l * 128 + ((1 ^ swz) << 2));
  const uint4* pC = (const uint4*)(sm + l * 128 + ((2 ^ swz) << 2));
  const uint4* pD = (const uint4*)(sm + l * 128 + ((3 ^ swz) << 2));
  const int jb = l * 8;
  uint hbits = 0;
#pragma unroll
  for (int jj = 7; jj >= 0; --jj) {
    uint4 wA = pA[jj * 4];
    uint4 wB = pB[jj * 4];
    uint4 wC = pC[jj * 4];
    uint4 wD = pD[jj * 4];
    int pc = 0;
    pc += __popc((curF[0]  ^ wA.x) & eF[0]);
    pc += __popc((curF[1]  ^ wA.y) & eF[1]);
    pc += __popc((curF[2]  ^ wA.z) & eF[2]);
    pc += __popc((curF[3]  ^ wA.w) & eF[3]);
    pc += __popc((curF[4]  ^ wB.x) & eF[4]);
    pc += __popc((curF[5]  ^ wB.y) & eF[5]);
    pc += __popc((curF[6]  ^ wB.z) & eF[6]);
    pc += __popc((curF[7]  ^ wB.w) & eF[7]);
    pc += __popc((curF[8]  ^ wC.x) & eF[8]);
    pc += __popc((curF[9]  ^ wC.y) & eF[9]);
    pc += __popc((curF[10] ^ wC.z) & eF[10]);
    pc += __popc((curF[11] ^ wC.w) & eF[11]);
    pc += __popc((curF[12] ^ wD.x) & eF[12]);
    pc += __popc((curF[13] ^ wD.y) & eF[13]);
    pc += __popc((curF[14] ^ wD.z) & eF[14]);
    pc += __popc((curF[15] ^ wD.w) & eF[15]);
    hbits = hbits + hbits + (uint)(madm2(pc, E) >= (int)sm[ST5 + jb + jj]);
  }
  uint hh = hbits << ((l & 3) * 8);
  uint h0 = (l < 4) ? hh : 0u;
  uint h1 = (l < 4) ? 0u : hh;
  h0 |= (uint)__shfl_xor((int)h0, 1); h0 |= (uint)__shfl_xor((int)h0, 2); h0 |= (uint)__shfl_xor((int)h0, 4);
  h1 |= (uint)__shfl_xor((int)h1, 1); h1 |= (uint)__shfl_xor((int)h1, 2); h1 |= (uint)__shfl_xor((int)h1, 4);

  // ---- fc2: 8 outputs per lane (raw T, value = 64 - 2*pc) ----
  const int c64 = 64;
  uint gbits = 0;
#pragma unroll
  for (int jj = 7; jj >= 0; --jj) {
    int pc = __popc(h0 ^ sm[SW2 + jb + jj]) + __popc(h1 ^ sm[SW2 + 64 + jb + jj]);
    gbits = gbits + gbits + (uint)(madm2(pc, c64) >= (int)sm[ST6 + jb + jj]);
  }
  uint gg = gbits << ((l & 3) * 8);
  uint g0 = (l < 4) ? gg : 0u;
  uint g1 = (l < 4) ? 0u : gg;
  g0 |= (uint)__shfl_xor((int)g0, 1); g0 |= (uint)__shfl_xor((int)g0, 2); g0 |= (uint)__shfl_xor((int)g0, 4);
  g1 |= (uint)__shfl_xor((int)g1, 1); g1 |= (uint)__shfl_xor((int)g1, 2); g1 |= (uint)__shfl_xor((int)g1, 4);

  // ---- fc3 + sigmoid ----
  if (l == 0) {
    int pc = __popc(g0 ^ sm[SW3]) + __popc(g1 ^ sm[SW3 + 1]);
    float z = __fadd_rn((float)(64 - 2 * pc), __uint_as_float(sm[SFB3]));
    out[b] = 1.f / (1.f + expf(-z));
  }
}

extern "C" void kernel_launch(void* const* d_in, const int* in_sizes, int n_in,
                              void* d_out, int out_size, void* d_ws, size_t ws_size,
                              hipStream_t stream) {
  const float* x       = (const float*)d_in[0];
  const float* conv0_w = (const float*)d_in[1];
  const float* conv0_b = (const float*)d_in[2];
  const float* bn0_g   = (const float*)d_in[3];
  const float* bn0_b   = (const float*)d_in[4];
  const float* bn0_m   = (const float*)d_in[5];
  const float* bn0_v   = (const float*)d_in[6];
  const float* convs_w = (const float*)d_in[7];
  const float* convs_b = (const float*)d_in[8];
  const float* bns_g   = (const float*)d_in[9];
  const float* bns_b   = (const float*)d_in[10];
  const float* bns_m   = (const float*)d_in[11];
  const float* bns_v   = (const float*)d_in[12];
  const float* fc1_w   = (const float*)d_in[13];
  const float* fc1_b   = (const float*)d_in[14];
  const float* bn5_g   = (const float*)d_in[15];
  const float* bn5_b   = (const float*)d_in[16];
  const float* bn5_m   = (const float*)d_in[17];
  const float* bn5_v   = (const float*)d_in[18];
  const float* fc2_w   = (const float*)d_in[19];
  const float* fc2_b   = (const float*)d_in[20];
  const float* bn6_g   = (const float*)d_in[21];
  const float* bn6_b   = (const float*)d_in[22];
  const float* bn6_m   = (const float*)d_in[23];
  const float* bn6_v   = (const float*)d_in[24];
  const float* fc3_w   = (const float*)d_in[25];
  const float* fc3_b   = (const float*)d_in[26];
  uint* ws = (uint*)d_ws;

  hipLaunchKernelGGL(prep_kernel, dim3(6), dim3(256), 0, stream,
                     conv0_w, conv0_b, bn0_g, bn0_b, bn0_m, bn0_v,
                     convs_w, convs_b, bns_g, bns_b, bns_m, bns_v,
                     fc1_w, fc1_b, bn5_g, bn5_b, bn5_m, bn5_v,
                     fc2_w, fc2_b, bn6_g, bn6_b, bn6_m, bn6_v,
                     fc3_w, fc3_b, ws);

  const int B = in_sizes[0] / 64;   // 65536
  const int threads = B * 8;        // 8 lanes per sample
  hipLaunchKernelGGL(bnn_kernel, dim3((threads + 255) / 256), dim3(256), 0, stream,
                     x, ws, (float*)d_out, B);
}